// Round 19
// baseline (60.952 us; speedup 1.0000x reference)
//
#include <hip/hip_runtime.h>

typedef __attribute__((ext_vector_type(8))) short bf16x8;
typedef __attribute__((ext_vector_type(4))) float f32x4;
typedef __attribute__((ext_vector_type(8))) unsigned short u16x8;

#define BB 32
#define NN 1024
#define MM 256
#define HH 128

__device__ __forceinline__ unsigned short f2bf(float f) {
  union { float f; unsigned int u; } c; c.f = f;
  unsigned int u = c.u + 0x7fffu + ((c.u >> 16) & 1u);  // RNE
  return (unsigned short)(u >> 16);
}
__device__ __forceinline__ unsigned int cvtpk(float lo, float hi) {
  unsigned int r;
  asm("v_cvt_pk_bf16_f32 %0, %1, %2" : "=v"(r) : "v"(lo), "v"(hi));
  return r;
}
__device__ __forceinline__ float4 gload_f4(const float* p) {
  float4 r;
  asm volatile("global_load_dwordx4 %0, %1, off" : "=v"(r) : "v"(p));
  return r;
}
typedef __attribute__((address_space(3))) unsigned int as3_u32;
typedef const __attribute__((address_space(1))) unsigned int as1_u32;
__device__ __forceinline__ void gl_lds16(const void* g, void* l) {
  __builtin_amdgcn_global_load_lds((as1_u32*)g, (as3_u32*)l, 16, 0, 0);
}

// ---------- combined pre-pass: hT (bf16 [B][M][N]) + W1T/W2T ----------
__global__ __launch_bounds__(256)
void k_prep(const float* __restrict__ hg, unsigned short* __restrict__ hTg,
            const float* __restrict__ W1, const float* __restrict__ W2,
            unsigned short* __restrict__ W1T, unsigned short* __restrict__ W2T) {
  int bid = blockIdx.x;
  if (bid < BB * 64) {
    __shared__ unsigned short tile[64][65];
    int b = bid >> 6;
    int t = bid & 63;
    int k0 = (t >> 2) << 6;
    int m0 = (t & 3) << 6;
    int tt = threadIdx.x;
    {
      int r = tt >> 2;
      int cg = (tt & 3) << 4;
      const float* src = hg + (((size_t)b * NN + k0 + r) * MM + m0 + cg);
#pragma unroll
      for (int i = 0; i < 4; ++i) {
        float4 v = reinterpret_cast<const float4*>(src)[i];
        tile[r][cg + i * 4 + 0] = f2bf(v.x);
        tile[r][cg + i * 4 + 1] = f2bf(v.y);
        tile[r][cg + i * 4 + 2] = f2bf(v.z);
        tile[r][cg + i * 4 + 3] = f2bf(v.w);
      }
    }
    __syncthreads();
    {
      int mr = tt >> 2;
      int kc = (tt & 3) << 4;
      alignas(16) unsigned short tmp[16];
#pragma unroll
      for (int i = 0; i < 16; ++i) tmp[i] = tile[kc + i][mr];
      unsigned short* dst = hTg + (((size_t)b * MM + m0 + mr) * NN + k0 + kc);
      *reinterpret_cast<u16x8*>(dst)     = *reinterpret_cast<u16x8*>(tmp);
      *reinterpret_cast<u16x8*>(dst + 8) = *reinterpret_cast<u16x8*>(tmp + 8);
    }
  } else {
    int idx = (bid - BB * 64) * 256 + threadIdx.x;
    if (idx < MM * HH) {
      int hc = idx >> 8;
      int m  = idx & 255;
      W1T[idx] = f2bf(W1[m * HH + hc]);
    } else {
      int j = idx - MM * HH;
      int m  = j >> 7;
      int hd = j & 127;
      W2T[j] = f2bf(W2[hd * MM + m]);
    }
  }
}

// ---------------- fused main ----------------
// 512 blocks x 512 threads (8 waves = 2 row-halves x 4 col-quarters).
// Block tile 64 x 256; BK=32, 32 K-steps. LDS 40960 B -> 3-4 blocks/CU
// (the concurrency push: more independent barrier groups to smooth the
// barrier-locked memory bursts that cap FETCH at ~1.1 TB/s).
// A: 1 pinned float4/thread/step (8-row x 128B contiguous runs), 2-deep
//    X/Y; LDS [64 rows][64B], 8B-slot XOR ^(row&3)<<4 (write 8B halves,
//    read 16B slots -- consistency verified symbolically).
// H: 2 gl_lds/thread/step; LDS [256 cols][64B], 16B-slot XOR ^(col&3)<<4,
//    pre-swizzled global source (rule 21).
// Per step: STAGE_H(t+1) -> ISSUE_A(t+2) -> CONSUME(t) (6 ds_read_b128 +
//   8 MFMA) -> VMW(3) [A(t+1) landed, 1.5 steps old] -> CVTWR A(t+1) ->
//   VMW(1) [H(t+1) in LDS; A(t+2) flies across barrier] -> lgkm-barrier.
// LDS map: H0@0(16K) H1@16K(16K) A0@32K(4K) A1@36K(4K) = 40960.
//   phase2 alias: Kld [64][512B]=32K @0; Cld [64][256B]=16K @0 (after
//   GEMM1 sync, r10-verified); smax (float[64]) @32K (A0 dead).
#define HB0 0
#define HB1 16384
#define AB0 32768
#define AB1 36864
#define KLD 0
#define CLD 0
#define SMAXOFF 32768

#define PIPE_BARRIER() do { \
  asm volatile("s_waitcnt lgkmcnt(0)" ::: "memory"); \
  __builtin_amdgcn_s_barrier(); \
  asm volatile("" ::: "memory"); } while (0)

#define VMW(N) do { asm volatile("s_waitcnt vmcnt(" #N ")" ::: "memory"); \
  __builtin_amdgcn_sched_barrier(0); } while (0)

__global__ __launch_bounds__(512)
void k_fused(const float* __restrict__ Ag, const float* __restrict__ hg,
             const unsigned short* __restrict__ hTg,
             const unsigned short* __restrict__ W1Tg,
             const unsigned short* __restrict__ W2Tg,
             const float* __restrict__ b1g, const float* __restrict__ b2g,
             float* __restrict__ outg) {
  __shared__ __align__(16) char smem[40960];
  float* smax = reinterpret_cast<float*>(smem + SMAXOFF);

  const int tid  = threadIdx.x;
  const int lane = tid & 63;
  const int wid  = tid >> 6;       // 0..7
  const int wr   = wid >> 2;       // 0..1 (row half, 32 rows)
  const int wc   = wid & 3;        // 0..3 (col quarter, 64 cols)
  const int l15  = lane & 15;
  const int lg   = lane >> 4;      // 0..3

  const int bid = blockIdx.x;
  const int b   = bid & 31;        // same-batch blocks share bid%8 -> same XCD
  const int r0  = (bid >> 5) << 6; // 16 row-blocks of 64

  const float* Ab = Ag + ((size_t)b * NN + r0) * NN;
  const unsigned short* hTb = hTg + (size_t)b * MM * NN;

  // ---- A staging: thread -> row tid>>3, fp32 quad tid&7 (128B runs) ----
  const int arow = tid >> 3;           // 0..63
  const int aq   = tid & 7;            // 4-float quad -> 8B bf16 half-slot
  const float* apA = Ab + (size_t)arow * NN + (aq << 2);
  const int awb = arow * 64 + (((aq << 3)) ^ ((arow & 3) << 4));

  // ---- H staging: chunk c = i*512+tid -> col=c>>2, 16B slot c&3;
  //      source pre-swizzled: slot sl holds hT[col][k0 + (sl^(col&3))*8] ----
  const unsigned short* baseH[2];
#pragma unroll
  for (int i = 0; i < 2; ++i) {
    int c = i * 512 + tid;
    int col = c >> 2, sl = c & 3;
    baseH[i] = hTb + (size_t)col * NN + ((sl ^ (col & 3)) << 3);
  }
  const int dstW = wid << 10;          // wave-uniform base (64 lanes x 16B)

#define STAGE_H(K0, HB)                                                     \
  do {                                                                      \
    gl_lds16(baseH[0] + (K0), smem + (HB) + dstW);                          \
    gl_lds16(baseH[1] + (K0), smem + (HB) + 8192 + dstW);                   \
  } while (0)

  float4 rAX, rAY;                      // 2-deep pinned A sets (4 VGPR each)
#define ISSUE_AX(K0) do { rAX = gload_f4(apA + (K0)); } while (0)
#define ISSUE_AY(K0) do { rAY = gload_f4(apA + (K0)); } while (0)

  float pmax = -1e30f;
#define CVTWR(AB, R)                                                        \
  do {                                                                      \
    pmax = fmaxf(pmax, fmaxf(fmaxf((R).x, (R).y), fmaxf((R).z, (R).w)));    \
    uint2 q = make_uint2(cvtpk((R).x, (R).y), cvtpk((R).z, (R).w));         \
    *reinterpret_cast<uint2*>(smem + (AB) + awb) = q;                       \
  } while (0)

  f32x4 acc[2][4];
#pragma unroll
  for (int m = 0; m < 2; ++m)
#pragma unroll
    for (int n = 0; n < 4; ++n) acc[m][n] = f32x4{0.f, 0.f, 0.f, 0.f};

#define CONSUME(AB, HB)                                                     \
  do {                                                                      \
    bf16x8 af[2], bh[4];                                                    \
    _Pragma("unroll")                                                       \
    for (int m = 0; m < 2; ++m) {                                           \
      int row = (wr << 5) + (m << 4) + l15;                                 \
      af[m] = *reinterpret_cast<const bf16x8*>(                             \
          smem + (AB) + row * 64 + ((lg << 4) ^ ((row & 3) << 4)));         \
    }                                                                       \
    _Pragma("unroll")                                                       \
    for (int n = 0; n < 4; ++n) {                                           \
      int col = (wc << 6) + (n << 4) + l15;                                 \
      bh[n] = *reinterpret_cast<const bf16x8*>(                             \
          smem + (HB) + col * 64 + ((lg << 4) ^ ((col & 3) << 4)));         \
    }                                                                       \
    _Pragma("unroll")                                                       \
    for (int m = 0; m < 2; ++m)                                             \
      _Pragma("unroll")                                                     \
      for (int n = 0; n < 4; ++n)                                           \
        acc[m][n] = __builtin_amdgcn_mfma_f32_16x16x32_bf16(af[m], bh[n],   \
                                                            acc[m][n], 0, 0, 0); \
  } while (0)

  // ---- prologue ----
  STAGE_H(0, HB0);
  ISSUE_AX(0);
  VMW(0);                          // H(0) in LDS, A(0) regs
  CVTWR(AB0, rAX);
  ISSUE_AY(32);                    // A(1) -> Y, flies across barrier
  PIPE_BARRIER();

  // ---- phase 1: 32 K-steps of 32, one barrier/step ----
#pragma unroll
  for (int t = 0; t < 32; ++t) {
    if (t < 31) STAGE_H((t + 1) * 32, (t & 1) ? HB0 : HB1);   // H(t+1): 2
    if (t < 30) {                                             // A(t+2): 1
      if (t & 1) ISSUE_AY((t + 2) * 32);
      else       ISSUE_AX((t + 2) * 32);
    }
    CONSUME((t & 1) ? AB1 : AB0, (t & 1) ? HB1 : HB0);
    if (t < 31) {
      if (t < 30) VMW(3); else VMW(2);   // retire A(t+1)
      if (t & 1) CVTWR(AB0, rAX);        // t odd: A(t+1) even -> X -> AB0
      else       CVTWR(AB1, rAY);        // t even: A(t+1) odd -> Y -> AB1
      if (t < 30) VMW(1); else VMW(0);   // retire H(t+1); A(t+2) keeps flying
      PIPE_BARRIER();
    }
  }

  // ---- rowmax finalize: 8 staging lanes per row (bits 0-2) ----
  {
    float v = pmax;
    v = fmaxf(v, __shfl_xor(v, 1));
    v = fmaxf(v, __shfl_xor(v, 2));
    v = fmaxf(v, __shfl_xor(v, 4));
    if ((tid & 7) == 0) smax[arow] = v;   // aliases AB0 (dead)
  }
  __syncthreads();   // phase-1 LDS fully retired before aliasing

  // ---- write k tile (/3, bf16) -> Kld [64][512B] XOR @0 ----
  {
    const float inv3 = 1.0f / 3.0f;
#pragma unroll
    for (int m = 0; m < 2; ++m)
#pragma unroll
      for (int n = 0; n < 4; ++n) {
        int col = (wc << 6) + (n << 4) + l15;
#pragma unroll
        for (int j = 0; j < 4; ++j) {
          int row = (wr << 5) + (m << 4) + (lg << 2) + j;
          *reinterpret_cast<unsigned short*>(smem + KLD + row * 512 +
                                             ((col * 2) ^ ((row & 7) << 4))) =
              f2bf(acc[m][n][j] * inv3);
        }
      }
  }
  __syncthreads();

  // ---- GEMM1: y[64][128] = k @ W1 (W1T fragments straight from L2) ----
  f32x4 acc1[2][2];
#pragma unroll
  for (int m = 0; m < 2; ++m)
#pragma unroll
    for (int n = 0; n < 2; ++n) acc1[m][n] = f32x4{0.f, 0.f, 0.f, 0.f};
  const int wcol1 = wc << 5;  // 0,32,64,96
#pragma unroll
  for (int kq = 0; kq < 8; ++kq) {
    bf16x8 af[2], bw[2];
#pragma unroll
    for (int m = 0; m < 2; ++m) {
      int row = (wr << 5) + (m << 4) + l15;
      af[m] = *reinterpret_cast<const bf16x8*>(smem + KLD + row * 512 +
              (((kq * 32 + (lg << 3)) * 2) ^ ((row & 7) << 4)));
    }
#pragma unroll
    for (int n = 0; n < 2; ++n) {
      int col = wcol1 + (n << 4) + l15;
      bw[n] = *reinterpret_cast<const bf16x8*>(W1Tg + (size_t)col * 256 +
                                               kq * 32 + (lg << 3));
    }
#pragma unroll
    for (int m = 0; m < 2; ++m)
#pragma unroll
      for (int n = 0; n < 2; ++n)
        acc1[m][n] = __builtin_amdgcn_mfma_f32_16x16x32_bf16(af[m], bw[n], acc1[m][n], 0, 0, 0);
  }
  __syncthreads();  // Kld fully read; Cld may overwrite

  // ---- c = relu(y+b1) -> Cld [64][256B] XOR @0 (aliases Kld) ----
  {
#pragma unroll
    for (int n = 0; n < 2; ++n) {
      int col = wcol1 + (n << 4) + l15;
      float bias = b1g[col];
#pragma unroll
      for (int m = 0; m < 2; ++m)
#pragma unroll
        for (int j = 0; j < 4; ++j) {
          int row = (wr << 5) + (m << 4) + (lg << 2) + j;
          float v = fmaxf(acc1[m][n][j] + bias, 0.f);
          *reinterpret_cast<unsigned short*>(smem + CLD + row * 256 +
                                             ((col * 2) ^ ((row & 7) << 4))) = f2bf(v);
        }
    }
  }
  __syncthreads();

  // ---- GEMM2: out2[64][256] = c @ W2 (W2T fragments from L2) ----
  f32x4 acc2[2][4];
#pragma unroll
  for (int m = 0; m < 2; ++m)
#pragma unroll
    for (int n = 0; n < 4; ++n) acc2[m][n] = f32x4{0.f, 0.f, 0.f, 0.f};
#pragma unroll
  for (int kq = 0; kq < 4; ++kq) {
    bf16x8 af[2], bw[4];
#pragma unroll
    for (int m = 0; m < 2; ++m) {
      int row = (wr << 5) + (m << 4) + l15;
      af[m] = *reinterpret_cast<const bf16x8*>(smem + CLD + row * 256 +
              (((kq * 32 + (lg << 3)) * 2) ^ ((row & 7) << 4)));
    }
#pragma unroll
    for (int n = 0; n < 4; ++n) {
      int col = (wc << 6) + (n << 4) + l15;
      bw[n] = *reinterpret_cast<const bf16x8*>(W2Tg + (size_t)col * 128 +
                                               kq * 32 + (lg << 3));
    }
#pragma unroll
    for (int m = 0; m < 2; ++m)
#pragma unroll
      for (int n = 0; n < 4; ++n)
        acc2[m][n] = __builtin_amdgcn_mfma_f32_16x16x32_bf16(af[m], bw[n], acc2[m][n], 0, 0, 0);
  }

  // ---- epilogue: out = (out2+b2)*mask + h*(1-mask) ----
  {
#pragma unroll
    for (int n = 0; n < 4; ++n) {
      int col = (wc << 6) + (n << 4) + l15;
      float b2v = b2g[col];
#pragma unroll
      for (int m = 0; m < 2; ++m)
#pragma unroll
        for (int j = 0; j < 4; ++j) {
          int row = (wr << 5) + (m << 4) + (lg << 2) + j;
          float kv = acc2[m][n][j] + b2v;
          float mask = smax[row];
          size_t gidx = ((size_t)b * NN + r0 + row) * MM + col;
          float hv = hg[gidx];
          outg[gidx] = kv * mask + hv * (1.f - mask);
        }
    }
  }
#undef CONSUME
#undef CVTWR
#undef ISSUE_AX
#undef ISSUE_AY
#undef STAGE_H
}

extern "C" void kernel_launch(void* const* d_in, const int* in_sizes, int n_in,
                              void* d_out, int out_size, void* d_ws, size_t ws_size,
                              hipStream_t stream) {
  (void)in_sizes; (void)n_in; (void)out_size; (void)ws_size;
  const float* A  = (const float*)d_in[0];
  const float* h  = (const float*)d_in[1];
  const float* W1 = (const float*)d_in[2];
  const float* b1 = (const float*)d_in[3];
  const float* W2 = (const float*)d_in[4];
  const float* b2 = (const float*)d_in[5];
  float* out = (float*)d_out;

  unsigned short* hT  = (unsigned short*)d_ws;
  unsigned short* W1T = (unsigned short*)((char*)d_ws + (size_t)BB * MM * NN * 2);
  unsigned short* W2T = W1T + MM * HH;

  k_prep<<<BB * 64 + 256, 256, 0, stream>>>(h, hT, W1, W2, W1T, W2T);
  k_fused<<<BB * 16, 512, 0, stream>>>(A, h, hT, W1T, W2T, b1, b2, out);
}